// Round 6
// baseline (942.871 us; speedup 1.0000x reference)
//
#include <hip/hip_runtime.h>
#include <cmath>

// Problem constants (fixed by the reference)
constexpr int TOT = 131072;   // 32 graphs * 4096 nodes
constexpr int NE  = 1048576;  // edges
constexpr int NMASK = 4095;   // N-1, N=4096

// Bucketed adjacency
constexpr int NB   = 512;     // buckets (dst >> 8)
constexpr int DPB  = 256;     // dsts per bucket
constexpr int BCAP = 4096;    // slots per bucket (mean 2048, Poisson max ~2350)
constexpr int EPB  = 8192;    // edges per partition block

typedef __attribute__((ext_vector_type(8))) short bf16x8;
typedef __attribute__((ext_vector_type(4))) float f32x4;

// ---- bf16 helpers (RNE) ----
__device__ inline float bf2f(unsigned int u16) {
    union { unsigned int i; float f; } x; x.i = u16 << 16; return x.f;
}
__device__ inline unsigned short f2bf(float f) {
    union { float f; unsigned int i; } x; x.f = f;
    unsigned int r = (x.i + 0x7fffu + ((x.i >> 16) & 1u)) >> 16;
    return (unsigned short)r;
}
__device__ inline void unpack8(uint4 v, float* f) {
    f[0] = bf2f(v.x & 0xffffu); f[1] = bf2f(v.x >> 16);
    f[2] = bf2f(v.y & 0xffffu); f[3] = bf2f(v.y >> 16);
    f[4] = bf2f(v.z & 0xffffu); f[5] = bf2f(v.z >> 16);
    f[6] = bf2f(v.w & 0xffffu); f[7] = bf2f(v.w >> 16);
}
__device__ inline uint4 pack8(const float* f) {
    uint4 v;
    v.x = (unsigned)f2bf(f[0]) | ((unsigned)f2bf(f[1]) << 16);
    v.y = (unsigned)f2bf(f[2]) | ((unsigned)f2bf(f[3]) << 16);
    v.z = (unsigned)f2bf(f[4]) | ((unsigned)f2bf(f[5]) << 16);
    v.w = (unsigned)f2bf(f[6]) | ((unsigned)f2bf(f[7]) << 16);
    return v;
}

// ================= edge partition by dst bucket =================
// gcur is line-padded (one int per 128B) so the 65K chunk-reservation
// atomics hit 512 independent lines instead of 16 shared ones.
__global__ __launch_bounds__(256) void k_part(const int* __restrict__ src,
                                              const int* __restrict__ dst,
                                              int* __restrict__ gcur,
                                              unsigned* __restrict__ buf) {
    __shared__ int hist[NB];
    __shared__ int cbase[NB];
    __shared__ int lcur[NB];
    const int tid = threadIdx.x;
    const int e0 = blockIdx.x * EPB;

    for (int b = tid; b < NB; b += 256) hist[b] = 0;
    __syncthreads();
    for (int i = tid; i < EPB; i += 256)
        atomicAdd(&hist[dst[e0 + i] >> 8], 1);
    __syncthreads();
    for (int b = tid; b < NB; b += 256) {
        int c = hist[b];
        cbase[b] = (c > 0) ? atomicAdd(&gcur[b * 32], c) : 0;
        lcur[b] = 0;
    }
    __syncthreads();
    for (int i = tid; i < EPB; i += 256) {
        int e = e0 + i;
        int d = dst[e];
        int b = d >> 8;
        int p = atomicAdd(&lcur[b], 1);
        buf[b * BCAP + cbase[b] + p] = ((unsigned)src[e] << 8) | (unsigned)(d & 255);
    }
}

// per-bucket degree histogram -> dinv
__global__ __launch_bounds__(256) void k_deghist(const unsigned* __restrict__ buf,
                                                 const int* __restrict__ gcur,
                                                 float* __restrict__ dinv) {
    __shared__ int cnt[DPB];
    const int b = blockIdx.x;
    const int tid = threadIdx.x;
    if (tid < DPB) cnt[tid] = 0;
    __syncthreads();
    const int n = gcur[b * 32];
    const unsigned* eb = buf + b * BCAP;
    for (int i = tid; i < n; i += 256)
        atomicAdd(&cnt[eb[i] & 255u], 1);
    __syncthreads();
    if (tid < DPB)
        dinv[(b << 8) + tid] = rsqrtf((float)cnt[tid] + 1.0f);   // +1 self-loop
}

// ================= weight packing into MFMA B-fragment order =================
__global__ __launch_bounds__(256) void k_packall(
    const float* __restrict__ W1, const float* __restrict__ W2, const float* __restrict__ W3,
    const float* __restrict__ tW1, const float* __restrict__ tW2, const float* __restrict__ tW3,
    unsigned short* __restrict__ g1, unsigned short* __restrict__ g2, unsigned short* __restrict__ g3,
    unsigned short* __restrict__ c1, unsigned short* __restrict__ c2, unsigned short* __restrict__ c3) {
    int gid = blockIdx.x * 256 + threadIdx.x;
    const float* w; unsigned short* wp; int CIN, COUT, taps, idx;
    if      (gid <  8192) { w = W1;  wp = g1; CIN = 64;  COUT = 128; taps = 1; idx = gid; }
    else if (gid < 12288) { w = W2;  wp = g2; CIN = 128; COUT = 32;  taps = 1; idx = gid - 8192; }
    else if (gid < 16384) { w = W3;  wp = g3; CIN = 32;  COUT = 128; taps = 1; idx = gid - 12288; }
    else if (gid < 65536) { w = tW1; wp = c1; CIN = 128; COUT = 128; taps = 3; idx = gid - 16384; }
    else if (gid < 77824) { w = tW2; wp = c2; CIN = 128; COUT = 32;  taps = 3; idx = gid - 65536; }
    else if (gid < 90112) { w = tW3; wp = c3; CIN = 32;  COUT = 128; taps = 3; idx = gid - 77824; }
    else return;
    int j = idx & 7;
    int L = (idx >> 3) & 63;
    int f = idx >> 9;
    int NT = COUT >> 4;
    int kc = f / NT, nt = f - kc * NT;
    int k = kc * 32 + (L >> 4) * 8 + j;
    int n = nt * 16 + (L & 15);
    float v;
    if (taps == 1) v = w[k * COUT + n];
    else { int t = k / CIN, c = k - t * CIN; v = w[(n * CIN + c) * 3 + t]; }
    wp[idx] = f2bf(v);
}

// ================= xs = x * dinv -> bf16 (64 ch) =================
__global__ __launch_bounds__(256) void k_scale64b(const float4* __restrict__ x,
                                                  const float* __restrict__ dinv,
                                                  uint4* __restrict__ out) {
    int t = blockIdx.x * 256 + threadIdx.x;   // t < TOT*8
    int row = t >> 3;
    float d = dinv[row];
    float4 v0 = x[t * 2], v1 = x[t * 2 + 1];
    float f[8] = { v0.x * d, v0.y * d, v0.z * d, v0.w * d,
                   v1.x * d, v1.y * d, v1.z * d, v1.w * d };
    out[t] = pack8(f);
}

// ================= bucket aggregation, 64 ch =================
// acc in LDS (256 dsts x 64 fp32 = 64 KB), XOR-swizzled by dstl&3 so the
// ds_add_f32 bank pattern (stride-64 floats) spreads across banks.
// out[d] = (xs[d] + sum_{e: dst=d} xs[src]) * dinv[d]
__global__ __launch_bounds__(256) void k_agg64(const uint4* __restrict__ xs,
                                               const unsigned* __restrict__ buf,
                                               const int* __restrict__ gcur,
                                               const float* __restrict__ dinv,
                                               uint4* __restrict__ out) {
    __shared__ float acc[DPB * 64];
    const int b = blockIdx.x;
    const int tid = threadIdx.x;
    for (int i = tid; i < DPB * 64; i += 256) acc[i] = 0.0f;
    __syncthreads();
    const int n = gcur[b * 32];
    const unsigned* eb = buf + b * BCAP;
    const int part = tid & 7;      // 16B channel-part
    const int eslot = tid >> 3;    // 32 edges per block pass
    for (int i0 = 0; i0 < n; i0 += 128) {
#pragma unroll
        for (int u = 0; u < 4; ++u) {
            int ei = i0 + u * 32 + eslot;
            if (ei < n) {
                unsigned w = eb[ei];
                int s = (int)(w >> 8), dl = (int)(w & 255u);
                float f[8];
                unpack8(xs[(s << 3) + part], f);
                int base = dl * 64, sw = (dl & 3) << 3;
#pragma unroll
                for (int j = 0; j < 8; ++j)
                    atomicAdd(&acc[base + ((part * 8 + j) ^ sw)], f[j]);
            }
        }
    }
    __syncthreads();
    for (int k = tid; k < DPB * 8; k += 256) {
        int dl = k >> 3, p = k & 7;
        int d = (b << 8) + dl;
        float f[8];
        unpack8(xs[(d << 3) + p], f);       // self-loop term
        int base = dl * 64, sw = (dl & 3) << 3;
        float dv = dinv[d];
#pragma unroll
        for (int j = 0; j < 8; ++j)
            f[j] = (f[j] + acc[base + ((p * 8 + j) ^ sw)]) * dv;
        out[(d << 3) + p] = pack8(f);
    }
}

// ================= bucket aggregation, 32 ch =================
// EPI==2: out = (self+sum) * dinv
// EPI==1: out = relu((self+sum)*dinv + bias) * dinv
template<int EPI>
__global__ __launch_bounds__(256) void k_agg32(const uint4* __restrict__ xs,
                                               const unsigned* __restrict__ buf,
                                               const int* __restrict__ gcur,
                                               const float* __restrict__ dinv,
                                               const float* __restrict__ bias,
                                               uint4* __restrict__ out) {
    __shared__ float acc[DPB * 32];
    const int b = blockIdx.x;
    const int tid = threadIdx.x;
    for (int i = tid; i < DPB * 32; i += 256) acc[i] = 0.0f;
    __syncthreads();
    const int n = gcur[b * 32];
    const unsigned* eb = buf + b * BCAP;
    const int part = tid & 3;      // 16B channel-part (4 per row)
    const int eslot = tid >> 2;    // 64 edges per block pass
    for (int i0 = 0; i0 < n; i0 += 256) {
#pragma unroll
        for (int u = 0; u < 4; ++u) {
            int ei = i0 + u * 64 + eslot;
            if (ei < n) {
                unsigned w = eb[ei];
                int s = (int)(w >> 8), dl = (int)(w & 255u);
                float f[8];
                unpack8(xs[(s << 2) + part], f);
                int base = dl * 32, sw = (dl & 3) << 3;
#pragma unroll
                for (int j = 0; j < 8; ++j)
                    atomicAdd(&acc[base + ((part * 8 + j) ^ sw)], f[j]);
            }
        }
    }
    __syncthreads();
    for (int k = tid; k < DPB * 4; k += 256) {
        int dl = k >> 2, p = k & 3;
        int d = (b << 8) + dl;
        float f[8];
        unpack8(xs[(d << 2) + p], f);       // self-loop term
        int base = dl * 32, sw = (dl & 3) << 3;
        float dv = dinv[d];
        if (EPI == 1) {
#pragma unroll
            for (int j = 0; j < 8; ++j) {
                float s = f[j] + acc[base + ((p * 8 + j) ^ sw)];
                f[j] = fmaxf(fmaf(s, dv, bias[p * 8 + j]), 0.0f) * dv;
            }
        } else {
#pragma unroll
            for (int j = 0; j < 8; ++j)
                f[j] = (f[j] + acc[base + ((p * 8 + j) ^ sw)]) * dv;
        }
        out[(d << 2) + p] = pack8(f);
    }
}

// ================= MFMA dense / conv1d =================
template<int CIN, int COUT, int TAPS, bool RELU, bool BIAS, bool SOUT>
__global__ __launch_bounds__(256) void k_mm(const unsigned short* __restrict__ x,
                                            const bf16x8* __restrict__ wp,
                                            const float* __restrict__ bias,
                                            const float* __restrict__ dinv,
                                            unsigned short* __restrict__ y) {
    constexpr int ROWS = 64;
    constexpr int HALO = (TAPS == 3) ? 1 : 0;
    constexpr int TR = ROWS + 2 * HALO;
    constexpr int SC = CIN + 8;
    constexpr int NCH = CIN / 32;
    constexpr int NK = TAPS * NCH;
    constexpr int NT = COUT / 16;
    constexpr int WN = (COUT == 128) ? 2 : 1;
    constexpr int WM = (COUT == 128) ? 4 : 2;
    __shared__ __attribute__((aligned(16))) unsigned short tile[TR * SC];

    const int R0 = blockIdx.x * ROWS;
    const int n0 = R0 & NMASK; (void)n0;

    constexpr int NLD = TR * (CIN / 8);
    for (int idx = threadIdx.x; idx < NLD; idx += 256) {
        int tr = idx / (CIN / 8);
        int c8 = idx - tr * (CIN / 8);
        int ro = tr - HALO;
        bool valid = true;
        if (TAPS == 3) {
            if (ro < 0) valid = (n0 > 0);
            else if (ro >= ROWS) valid = (n0 + ROWS < 4096);
        }
        uint4 v = make_uint4(0, 0, 0, 0);
        if (valid) v = *(const uint4*)(x + (long)(R0 + ro) * CIN + c8 * 8);
        *(uint4*)(tile + tr * SC + c8 * 8) = v;
    }
    __syncthreads();

    const int lane = threadIdx.x & 63;
    const int w = threadIdx.x >> 6;
    const int l16 = lane & 15;
    const int q = lane >> 4;
    const int colbase = (COUT == 128) ? w * 32 : (w & 1) * 16;
    const int rowbase = (COUT == 128) ? 0 : (w >> 1) * 32;
    const int nt0 = colbase >> 4;

    f32x4 acc[WM][WN];
#pragma unroll
    for (int wm = 0; wm < WM; ++wm)
#pragma unroll
        for (int nt = 0; nt < WN; ++nt) acc[wm][nt] = (f32x4){0.f, 0.f, 0.f, 0.f};

    const bf16x8* __restrict__ wpl = wp + lane;

#pragma unroll
    for (int kc = 0; kc < NK; ++kc) {
        const int tap = (TAPS == 3) ? (kc / NCH) : 0;
        const int ch  = (TAPS == 3) ? (kc - tap * NCH) : kc;
        bf16x8 a[WM];
#pragma unroll
        for (int wm = 0; wm < WM; ++wm)
            a[wm] = *(const bf16x8*)(tile + (rowbase + wm * 16 + l16 + tap) * SC + ch * 32 + q * 8);
        bf16x8 b[WN];
#pragma unroll
        for (int nt = 0; nt < WN; ++nt)
            b[nt] = wpl[(kc * NT + nt0 + nt) * 64];
#pragma unroll
        for (int wm = 0; wm < WM; ++wm)
#pragma unroll
            for (int nt = 0; nt < WN; ++nt)
                acc[wm][nt] = __builtin_amdgcn_mfma_f32_16x16x32_bf16(a[wm], b[nt], acc[wm][nt], 0, 0, 0);
    }

    // epilogue: C/D layout col=lane&15, row=q*4+reg
#pragma unroll
    for (int wm = 0; wm < WM; ++wm) {
#pragma unroll
        for (int nt = 0; nt < WN; ++nt) {
            int col = colbase + nt * 16 + l16;
            float bi = BIAS ? bias[col] : 0.0f;
#pragma unroll
            for (int r = 0; r < 4; ++r) {
                int row = R0 + rowbase + wm * 16 + q * 4 + r;
                float v = acc[wm][nt][r] + bi;
                if (RELU) v = fmaxf(v, 0.0f);
                if (SOUT) v *= dinv[row];
                y[(long)row * COUT + col] = f2bf(v);
            }
        }
    }
}

// ================= fused conv3 (32->128, k=3) + heads =================
// xt slab (64x128 bf16) staged in LDS at stride 130 (2-way bank alias = free),
// then 192 threads (wave-uniform head index -> scalar weight loads) do the
// three 128-wide dots. xt never touches HBM.
__global__ __launch_bounds__(256) void k_conv_heads(
    const unsigned short* __restrict__ x, const bf16x8* __restrict__ wp,
    const float* __restrict__ bias,
    const float* __restrict__ Wpi, const float* __restrict__ bpi,
    const float* __restrict__ Wn,  const float* __restrict__ bn,
    const float* __restrict__ Wp,  const float* __restrict__ bp,
    float* __restrict__ out) {
    constexpr int CIN = 32;
    constexpr int ROWS = 64, HALO = 1, TR = 66, SC = CIN + 8;
    constexpr int NK = 3, NT = 8, WN = 2, WM = 4;
    __shared__ __attribute__((aligned(16))) unsigned short tile[TR * SC];
    __shared__ unsigned short xts[64 * 130];

    const int R0 = blockIdx.x * ROWS;
    const int n0 = R0 & NMASK;

    constexpr int NLD = TR * (CIN / 8);
    for (int idx = threadIdx.x; idx < NLD; idx += 256) {
        int tr = idx / (CIN / 8);
        int c8 = idx - tr * (CIN / 8);
        int ro = tr - HALO;
        bool valid = true;
        if (ro < 0) valid = (n0 > 0);
        else if (ro >= ROWS) valid = (n0 + ROWS < 4096);
        uint4 v = make_uint4(0, 0, 0, 0);
        if (valid) v = *(const uint4*)(x + (long)(R0 + ro) * CIN + c8 * 8);
        *(uint4*)(tile + tr * SC + c8 * 8) = v;
    }
    __syncthreads();

    const int lane = threadIdx.x & 63;
    const int w = threadIdx.x >> 6;
    const int l16 = lane & 15;
    const int q = lane >> 4;
    const int colbase = w * 32;
    const int nt0 = colbase >> 4;

    f32x4 acc[WM][WN];
#pragma unroll
    for (int wm = 0; wm < WM; ++wm)
#pragma unroll
        for (int nt = 0; nt < WN; ++nt) acc[wm][nt] = (f32x4){0.f, 0.f, 0.f, 0.f};

    const bf16x8* __restrict__ wpl = wp + lane;

#pragma unroll
    for (int kc = 0; kc < NK; ++kc) {
        bf16x8 a[WM];
#pragma unroll
        for (int wm = 0; wm < WM; ++wm)
            a[wm] = *(const bf16x8*)(tile + (wm * 16 + l16 + kc) * SC + q * 8);
        bf16x8 b[WN];
#pragma unroll
        for (int nt = 0; nt < WN; ++nt)
            b[nt] = wpl[(kc * NT + nt0 + nt) * 64];
#pragma unroll
        for (int wm = 0; wm < WM; ++wm)
#pragma unroll
            for (int nt = 0; nt < WN; ++nt)
                acc[wm][nt] = __builtin_amdgcn_mfma_f32_16x16x32_bf16(a[wm], b[nt], acc[wm][nt], 0, 0, 0);
    }

    // stage xt slab (bf16 round-trip matches the old materialized path)
#pragma unroll
    for (int wm = 0; wm < WM; ++wm) {
#pragma unroll
        for (int nt = 0; nt < WN; ++nt) {
            int col = colbase + nt * 16 + l16;
            float bi = bias[col];
#pragma unroll
            for (int r = 0; r < 4; ++r) {
                int row = wm * 16 + q * 4 + r;
                xts[row * 130 + col] = f2bf(fmaxf(acc[wm][nt][r] + bi, 0.0f));
            }
        }
    }
    __syncthreads();
    if (threadIdx.x < 192) {
        int h = threadIdx.x >> 6;           // wave-uniform
        int row = threadIdx.x & 63;
        const float* Wh = (h == 0) ? Wpi : (h == 1) ? Wn : Wp;
        float s = 0.0f;
        const unsigned short* xr = xts + row * 130;
#pragma unroll
        for (int c2 = 0; c2 < 64; ++c2) {
            unsigned u = *(const unsigned*)(xr + c2 * 2);
            s = fmaf(bf2f(u & 0xffffu), Wh[c2 * 2], s);
            s = fmaf(bf2f(u >> 16), Wh[c2 * 2 + 1], s);
        }
        float bb = (h == 0) ? bpi[0] : (h == 1) ? bn[0] : bp[0];
        float z = s + bb;
        float o;
        if (h == 1) o = (z > 20.0f) ? z : log1pf(expf(z));
        else        o = 1.0f / (1.0f + expf(-z));
        out[h * TOT + R0 + row] = o;
    }
}

extern "C" void kernel_launch(void* const* d_in, const int* in_sizes, int n_in,
                              void* d_out, int out_size, void* d_ws, size_t ws_size,
                              hipStream_t stream) {
    const float* x   = (const float*)d_in[0];
    const int*   ei  = (const int*)d_in[1];
    const int*   src = ei;
    const int*   dst = ei + NE;
    const float* W1 = (const float*)d_in[3];
    const float* b1 = (const float*)d_in[4];
    const float* W2 = (const float*)d_in[5];
    const float* b2 = (const float*)d_in[6];
    const float* W3 = (const float*)d_in[7];
    const float* b3 = (const float*)d_in[8];
    const float* tW1 = (const float*)d_in[9];
    const float* tb1 = (const float*)d_in[10];
    const float* tW2 = (const float*)d_in[11];
    const float* tb2 = (const float*)d_in[12];
    const float* tW3 = (const float*)d_in[13];
    const float* tb3 = (const float*)d_in[14];
    const float* Wpi = (const float*)d_in[15];
    const float* bpi = (const float*)d_in[16];
    const float* Wn  = (const float*)d_in[17];
    const float* bn  = (const float*)d_in[18];
    const float* Wp  = (const float*)d_in[19];
    const float* bp  = (const float*)d_in[20];

    // ---- workspace layout ----
    char* ws = (char*)d_ws;
    float* dinv = (float*)(ws + (0ull << 20));            // 512 KB
    int*   gcur = (int*)  (ws + (1ull << 20));            // 64 KB (line-padded, NB*32 ints)
    unsigned short* wpG1 = (unsigned short*)(ws + (2ull << 20));
    unsigned short* wpG2 = (unsigned short*)(ws + (2ull << 20) + (128 << 10));
    unsigned short* wpG3 = (unsigned short*)(ws + (2ull << 20) + (256 << 10));
    unsigned short* wpC1 = (unsigned short*)(ws + (2ull << 20) + (384 << 10));
    unsigned short* wpC2 = (unsigned short*)(ws + (2ull << 20) + (512 << 10));
    unsigned short* wpC3 = (unsigned short*)(ws + (2ull << 20) + (640 << 10));
    unsigned* buf = (unsigned*)(ws + (4ull << 20));       // 8 MB (NB * BCAP * 4B)
    unsigned short* Xa = (unsigned short*)(ws + (16ull  << 20));  // 64ch  16.8 MB
    unsigned short* Xb = (unsigned short*)(ws + (36ull  << 20));  // 128ch 33.6 MB
    unsigned short* Xc = (unsigned short*)(ws + (72ull  << 20));  // 128ch 33.6 MB
    unsigned short* Xd = (unsigned short*)(ws + (108ull << 20));  // 32ch   8.4 MB
    unsigned short* Xe = (unsigned short*)(ws + (120ull << 20));  // 32ch   8.4 MB

    // ---- prep ----
    hipMemsetAsync(gcur, 0, NB * 32 * sizeof(int), stream);
    k_packall<<<352, 256, 0, stream>>>(W1, W2, W3, tW1, tW2, tW3,
                                       wpG1, wpG2, wpG3, wpC1, wpC2, wpC3);

    // ---- adjacency: bucket partition + degree hist ----
    k_part<<<NE / EPB, 256, 0, stream>>>(src, dst, gcur, buf);
    k_deghist<<<NB, 256, 0, stream>>>(buf, gcur, dinv);

    // ---- GCN layer 1: xs = x*dinv; agg; h1 = relu(agg1s@W1+b1) ----
    k_scale64b<<<TOT * 8 / 256, 256, 0, stream>>>((const float4*)x, dinv, (uint4*)Xa);
    k_agg64<<<NB, 256, 0, stream>>>((const uint4*)Xa, buf, gcur, dinv, (uint4*)Xb);
    k_mm<64, 128, 1, true, true, false>
        <<<TOT / 64, 256, 0, stream>>>(Xb, (const bf16x8*)wpG1, b1, dinv, Xc);

    // ---- GCN layer 2: zs2 = (h1@W2)*dinv; zs3 = relu(agg*dinv + b2)*dinv ----
    k_mm<128, 32, 1, false, false, true>
        <<<TOT / 64, 256, 0, stream>>>(Xc, (const bf16x8*)wpG2, nullptr, dinv, Xd);
    k_agg32<1><<<NB, 256, 0, stream>>>((const uint4*)Xd, buf, gcur, dinv, b2, (uint4*)Xe);

    // ---- GCN layer 3: agg3s = agg(zs3)*dinv; h3 = relu(agg3s@W3+b3) ----
    k_agg32<2><<<NB, 256, 0, stream>>>((const uint4*)Xe, buf, gcur, dinv, nullptr, (uint4*)Xd);
    k_mm<32, 128, 1, true, true, false>
        <<<TOT / 64, 256, 0, stream>>>(Xd, (const bf16x8*)wpG3, b3, dinv, Xb);

    // ---- temporal convs 1,2 ----
    k_mm<128, 128, 3, true, true, false>
        <<<TOT / 64, 256, 0, stream>>>(Xb, (const bf16x8*)wpC1, tb1, nullptr, Xc);
    k_mm<128, 32, 3, true, true, false>
        <<<TOT / 64, 256, 0, stream>>>(Xc, (const bf16x8*)wpC2, tb2, nullptr, Xd);

    // ---- conv3 + heads fused (xt never materialized) ----
    k_conv_heads<<<TOT / 64, 256, 0, stream>>>(Xd, (const bf16x8*)wpC3, tb3,
                                               Wpi, bpi, Wn, bn, Wp, bp, (float*)d_out);
}

// Round 7
// 301.428 us; speedup vs baseline: 3.1280x; 3.1280x over previous
//
#include <hip/hip_runtime.h>
#include <cmath>

// Problem constants (fixed by the reference)
constexpr int TOT = 131072;   // 32 graphs * 4096 nodes
constexpr int NE  = 1048576;  // edges
constexpr int NMASK = 4095;   // N-1, N=4096

// Bucketed adjacency
constexpr int NB   = 512;     // buckets (dst >> 8)
constexpr int DPB  = 256;     // dsts per bucket
constexpr int BCAP = 4096;    // slots per bucket (mean 2048, ~45 sigma headroom)
constexpr int EPB  = 8192;    // edges per partition block

typedef __attribute__((ext_vector_type(8))) short bf16x8;
typedef __attribute__((ext_vector_type(4))) float f32x4;

// ---- bf16 helpers (RNE) ----
__device__ inline float bf2f(unsigned int u16) {
    union { unsigned int i; float f; } x; x.i = u16 << 16; return x.f;
}
__device__ inline unsigned short f2bf(float f) {
    union { float f; unsigned int i; } x; x.f = f;
    unsigned int r = (x.i + 0x7fffu + ((x.i >> 16) & 1u)) >> 16;
    return (unsigned short)r;
}
__device__ inline void unpack8(uint4 v, float* f) {
    f[0] = bf2f(v.x & 0xffffu); f[1] = bf2f(v.x >> 16);
    f[2] = bf2f(v.y & 0xffffu); f[3] = bf2f(v.y >> 16);
    f[4] = bf2f(v.z & 0xffffu); f[5] = bf2f(v.z >> 16);
    f[6] = bf2f(v.w & 0xffffu); f[7] = bf2f(v.w >> 16);
}
__device__ inline uint4 pack8(const float* f) {
    uint4 v;
    v.x = (unsigned)f2bf(f[0]) | ((unsigned)f2bf(f[1]) << 16);
    v.y = (unsigned)f2bf(f[2]) | ((unsigned)f2bf(f[3]) << 16);
    v.z = (unsigned)f2bf(f[4]) | ((unsigned)f2bf(f[5]) << 16);
    v.w = (unsigned)f2bf(f[6]) | ((unsigned)f2bf(f[7]) << 16);
    return v;
}

// ================= edge partition by dst bucket (proven in round 6) =================
__global__ __launch_bounds__(256) void k_part(const int* __restrict__ src,
                                              const int* __restrict__ dst,
                                              int* __restrict__ gcur,
                                              unsigned* __restrict__ buf) {
    __shared__ int hist[NB];
    __shared__ int cbase[NB];
    __shared__ int lcur[NB];
    const int tid = threadIdx.x;
    const int e0 = blockIdx.x * EPB;

    for (int b = tid; b < NB; b += 256) hist[b] = 0;
    __syncthreads();
    for (int i = tid; i < EPB; i += 256)
        atomicAdd(&hist[dst[e0 + i] >> 8], 1);
    __syncthreads();
    for (int b = tid; b < NB; b += 256) {
        int c = hist[b];
        cbase[b] = (c > 0) ? atomicAdd(&gcur[b * 32], c) : 0;
        lcur[b] = 0;
    }
    __syncthreads();
    for (int i = tid; i < EPB; i += 256) {
        int e = e0 + i;
        int d = dst[e];
        int b = d >> 8;
        int p = atomicAdd(&lcur[b], 1);
        buf[b * BCAP + cbase[b] + p] = ((unsigned)src[e] << 8) | (unsigned)(d & 255);
    }
}

// ================= per-bucket CSR build =================
// LDS histogram -> LDS exclusive scan -> LDS-cursor reorder. adj writes land
// in this bucket's 16 KB window (single block, single XCD: no cross-XCD
// write amplification). Also emits rse[d]={start,count} and dinv.
__global__ __launch_bounds__(256) void k_bcsr(const unsigned* __restrict__ buf,
                                              const int* __restrict__ gcur,
                                              int* __restrict__ adj,
                                              int2* __restrict__ rse,
                                              float* __restrict__ dinv) {
    __shared__ int cnt[DPB];
    __shared__ int start[DPB];
    __shared__ int cur[DPB];
    __shared__ int sc[DPB];
    const int b = blockIdx.x;
    const int tid = threadIdx.x;
    cnt[tid] = 0;
    __syncthreads();
    const int n = gcur[b * 32];
    const unsigned* eb = buf + b * BCAP;
    for (int i = tid; i < n; i += 256)
        atomicAdd(&cnt[eb[i] & 255u], 1);
    __syncthreads();
    int v = cnt[tid];
    sc[tid] = v;
    __syncthreads();
    for (int off = 1; off < 256; off <<= 1) {
        int a = sc[tid];
        int p = (tid >= off) ? sc[tid - off] : 0;
        __syncthreads();
        sc[tid] = a + p;
        __syncthreads();
    }
    int st = sc[tid] - v;
    start[tid] = st;
    cur[tid] = 0;
    int d = (b << 8) + tid;
    rse[d] = make_int2(b * BCAP + st, v);
    dinv[d] = rsqrtf((float)v + 1.0f);   // +1 self-loop
    __syncthreads();
    for (int i = tid; i < n; i += 256) {
        unsigned w = eb[i];
        int dl = (int)(w & 255u);
        int p = atomicAdd(&cur[dl], 1);
        adj[b * BCAP + start[dl] + p] = (int)(w >> 8);
    }
}

// ================= weight packing into MFMA B-fragment order =================
__global__ __launch_bounds__(256) void k_packall(
    const float* __restrict__ W1, const float* __restrict__ W2, const float* __restrict__ W3,
    const float* __restrict__ tW1, const float* __restrict__ tW2, const float* __restrict__ tW3,
    unsigned short* __restrict__ g1, unsigned short* __restrict__ g2, unsigned short* __restrict__ g3,
    unsigned short* __restrict__ c1, unsigned short* __restrict__ c2, unsigned short* __restrict__ c3) {
    int gid = blockIdx.x * 256 + threadIdx.x;
    const float* w; unsigned short* wp; int CIN, COUT, taps, idx;
    if      (gid <  8192) { w = W1;  wp = g1; CIN = 64;  COUT = 128; taps = 1; idx = gid; }
    else if (gid < 12288) { w = W2;  wp = g2; CIN = 128; COUT = 32;  taps = 1; idx = gid - 8192; }
    else if (gid < 16384) { w = W3;  wp = g3; CIN = 32;  COUT = 128; taps = 1; idx = gid - 12288; }
    else if (gid < 65536) { w = tW1; wp = c1; CIN = 128; COUT = 128; taps = 3; idx = gid - 16384; }
    else if (gid < 77824) { w = tW2; wp = c2; CIN = 128; COUT = 32;  taps = 3; idx = gid - 65536; }
    else if (gid < 90112) { w = tW3; wp = c3; CIN = 32;  COUT = 128; taps = 3; idx = gid - 77824; }
    else return;
    int j = idx & 7;
    int L = (idx >> 3) & 63;
    int f = idx >> 9;
    int NT = COUT >> 4;
    int kc = f / NT, nt = f - kc * NT;
    int k = kc * 32 + (L >> 4) * 8 + j;
    int n = nt * 16 + (L & 15);
    float v;
    if (taps == 1) v = w[k * COUT + n];
    else { int t = k / CIN, c = k - t * CIN; v = w[(n * CIN + c) * 3 + t]; }
    wp[idx] = f2bf(v);
}

// ================= xs = x * dinv -> bf16 (64 ch) =================
__global__ __launch_bounds__(256) void k_scale64b(const float4* __restrict__ x,
                                                  const float* __restrict__ dinv,
                                                  uint4* __restrict__ out) {
    int t = blockIdx.x * 256 + threadIdx.x;   // t < TOT*8
    int row = t >> 3;
    float d = dinv[row];
    float4 v0 = x[t * 2], v1 = x[t * 2 + 1];
    float f[8] = { v0.x * d, v0.y * d, v0.z * d, v0.w * d,
                   v1.x * d, v1.y * d, v1.z * d, v1.w * d };
    out[t] = pack8(f);
}

// ================= CSR gather (4-way ILP, no chains, no atomics) =================
// LC = log2(C/8) threads per row.
// EPI==2: out = (self+sum) * dinv
// EPI==1: out = relu((self+sum)*dinv + bias) * dinv
template<int LC, int EPI>
__global__ __launch_bounds__(256) void k_gcsr(const uint4* __restrict__ xs,
                                              const int* __restrict__ adj,
                                              const int2* __restrict__ rse,
                                              const float* __restrict__ dinv,
                                              const float* __restrict__ bias,
                                              uint4* __restrict__ out) {
    int t = blockIdx.x * 256 + threadIdx.x;   // t < TOT << LC
    int d = t >> LC;
    int g = t & ((1 << LC) - 1);
    float a[8];
    unpack8(xs[t], a);                        // self-loop term
    int2 se = rse[d];
    int e = se.x, end = se.x + se.y;
    for (; e + 4 <= end; e += 4) {
        int s0 = adj[e], s1 = adj[e + 1], s2 = adj[e + 2], s3 = adj[e + 3];
        uint4 v0 = xs[(s0 << LC) + g];
        uint4 v1 = xs[(s1 << LC) + g];
        uint4 v2 = xs[(s2 << LC) + g];
        uint4 v3 = xs[(s3 << LC) + g];
        float f[8];
        unpack8(v0, f);
#pragma unroll
        for (int j = 0; j < 8; ++j) a[j] += f[j];
        unpack8(v1, f);
#pragma unroll
        for (int j = 0; j < 8; ++j) a[j] += f[j];
        unpack8(v2, f);
#pragma unroll
        for (int j = 0; j < 8; ++j) a[j] += f[j];
        unpack8(v3, f);
#pragma unroll
        for (int j = 0; j < 8; ++j) a[j] += f[j];
    }
    for (; e < end; ++e) {
        float f[8];
        unpack8(xs[(adj[e] << LC) + g], f);
#pragma unroll
        for (int j = 0; j < 8; ++j) a[j] += f[j];
    }
    float dv = dinv[d];
    if (EPI == 1) {
#pragma unroll
        for (int j = 0; j < 8; ++j)
            a[j] = fmaxf(fmaf(a[j], dv, bias[g * 8 + j]), 0.0f) * dv;
    } else {
#pragma unroll
        for (int j = 0; j < 8; ++j) a[j] *= dv;
    }
    out[t] = pack8(a);
}

// ================= MFMA dense / conv1d =================
template<int CIN, int COUT, int TAPS, bool RELU, bool BIAS, bool SOUT>
__global__ __launch_bounds__(256) void k_mm(const unsigned short* __restrict__ x,
                                            const bf16x8* __restrict__ wp,
                                            const float* __restrict__ bias,
                                            const float* __restrict__ dinv,
                                            unsigned short* __restrict__ y) {
    constexpr int ROWS = 64;
    constexpr int HALO = (TAPS == 3) ? 1 : 0;
    constexpr int TR = ROWS + 2 * HALO;
    constexpr int SC = CIN + 8;
    constexpr int NCH = CIN / 32;
    constexpr int NK = TAPS * NCH;
    constexpr int NT = COUT / 16;
    constexpr int WN = (COUT == 128) ? 2 : 1;
    constexpr int WM = (COUT == 128) ? 4 : 2;
    __shared__ __attribute__((aligned(16))) unsigned short tile[TR * SC];

    const int R0 = blockIdx.x * ROWS;
    const int n0 = R0 & NMASK; (void)n0;

    constexpr int NLD = TR * (CIN / 8);
    for (int idx = threadIdx.x; idx < NLD; idx += 256) {
        int tr = idx / (CIN / 8);
        int c8 = idx - tr * (CIN / 8);
        int ro = tr - HALO;
        bool valid = true;
        if (TAPS == 3) {
            if (ro < 0) valid = (n0 > 0);
            else if (ro >= ROWS) valid = (n0 + ROWS < 4096);
        }
        uint4 v = make_uint4(0, 0, 0, 0);
        if (valid) v = *(const uint4*)(x + (long)(R0 + ro) * CIN + c8 * 8);
        *(uint4*)(tile + tr * SC + c8 * 8) = v;
    }
    __syncthreads();

    const int lane = threadIdx.x & 63;
    const int w = threadIdx.x >> 6;
    const int l16 = lane & 15;
    const int q = lane >> 4;
    const int colbase = (COUT == 128) ? w * 32 : (w & 1) * 16;
    const int rowbase = (COUT == 128) ? 0 : (w >> 1) * 32;
    const int nt0 = colbase >> 4;

    f32x4 acc[WM][WN];
#pragma unroll
    for (int wm = 0; wm < WM; ++wm)
#pragma unroll
        for (int nt = 0; nt < WN; ++nt) acc[wm][nt] = (f32x4){0.f, 0.f, 0.f, 0.f};

    const bf16x8* __restrict__ wpl = wp + lane;

#pragma unroll
    for (int kc = 0; kc < NK; ++kc) {
        const int tap = (TAPS == 3) ? (kc / NCH) : 0;
        const int ch  = (TAPS == 3) ? (kc - tap * NCH) : kc;
        bf16x8 a[WM];
#pragma unroll
        for (int wm = 0; wm < WM; ++wm)
            a[wm] = *(const bf16x8*)(tile + (rowbase + wm * 16 + l16 + tap) * SC + ch * 32 + q * 8);
        bf16x8 b[WN];
#pragma unroll
        for (int nt = 0; nt < WN; ++nt)
            b[nt] = wpl[(kc * NT + nt0 + nt) * 64];
#pragma unroll
        for (int wm = 0; wm < WM; ++wm)
#pragma unroll
            for (int nt = 0; nt < WN; ++nt)
                acc[wm][nt] = __builtin_amdgcn_mfma_f32_16x16x32_bf16(a[wm], b[nt], acc[wm][nt], 0, 0, 0);
    }

    // epilogue: C/D layout col=lane&15, row=q*4+reg
#pragma unroll
    for (int wm = 0; wm < WM; ++wm) {
#pragma unroll
        for (int nt = 0; nt < WN; ++nt) {
            int col = colbase + nt * 16 + l16;
            float bi = BIAS ? bias[col] : 0.0f;
#pragma unroll
            for (int r = 0; r < 4; ++r) {
                int row = R0 + rowbase + wm * 16 + q * 4 + r;
                float v = acc[wm][nt][r] + bi;
                if (RELU) v = fmaxf(v, 0.0f);
                if (SOUT) v *= dinv[row];
                y[(long)row * COUT + col] = f2bf(v);
            }
        }
    }
}

// ================= fused conv3 (32->128, k=3) + heads =================
__global__ __launch_bounds__(256) void k_conv_heads(
    const unsigned short* __restrict__ x, const bf16x8* __restrict__ wp,
    const float* __restrict__ bias,
    const float* __restrict__ Wpi, const float* __restrict__ bpi,
    const float* __restrict__ Wn,  const float* __restrict__ bn,
    const float* __restrict__ Wp,  const float* __restrict__ bp,
    float* __restrict__ out) {
    constexpr int CIN = 32;
    constexpr int ROWS = 64, HALO = 1, TR = 66, SC = CIN + 8;
    constexpr int NK = 3, NT = 8, WN = 2, WM = 4;
    __shared__ __attribute__((aligned(16))) unsigned short tile[TR * SC];
    __shared__ unsigned short xts[64 * 130];

    const int R0 = blockIdx.x * ROWS;
    const int n0 = R0 & NMASK;

    constexpr int NLD = TR * (CIN / 8);
    for (int idx = threadIdx.x; idx < NLD; idx += 256) {
        int tr = idx / (CIN / 8);
        int c8 = idx - tr * (CIN / 8);
        int ro = tr - HALO;
        bool valid = true;
        if (ro < 0) valid = (n0 > 0);
        else if (ro >= ROWS) valid = (n0 + ROWS < 4096);
        uint4 v = make_uint4(0, 0, 0, 0);
        if (valid) v = *(const uint4*)(x + (long)(R0 + ro) * CIN + c8 * 8);
        *(uint4*)(tile + tr * SC + c8 * 8) = v;
    }
    __syncthreads();

    const int lane = threadIdx.x & 63;
    const int w = threadIdx.x >> 6;
    const int l16 = lane & 15;
    const int q = lane >> 4;
    const int colbase = w * 32;
    const int nt0 = colbase >> 4;

    f32x4 acc[WM][WN];
#pragma unroll
    for (int wm = 0; wm < WM; ++wm)
#pragma unroll
        for (int nt = 0; nt < WN; ++nt) acc[wm][nt] = (f32x4){0.f, 0.f, 0.f, 0.f};

    const bf16x8* __restrict__ wpl = wp + lane;

#pragma unroll
    for (int kc = 0; kc < NK; ++kc) {
        bf16x8 a[WM];
#pragma unroll
        for (int wm = 0; wm < WM; ++wm)
            a[wm] = *(const bf16x8*)(tile + (wm * 16 + l16 + kc) * SC + q * 8);
        bf16x8 b[WN];
#pragma unroll
        for (int nt = 0; nt < WN; ++nt)
            b[nt] = wpl[(kc * NT + nt0 + nt) * 64];
#pragma unroll
        for (int wm = 0; wm < WM; ++wm)
#pragma unroll
            for (int nt = 0; nt < WN; ++nt)
                acc[wm][nt] = __builtin_amdgcn_mfma_f32_16x16x32_bf16(a[wm], b[nt], acc[wm][nt], 0, 0, 0);
    }

    // stage xt slab (bf16 round-trip matches the old materialized path)
#pragma unroll
    for (int wm = 0; wm < WM; ++wm) {
#pragma unroll
        for (int nt = 0; nt < WN; ++nt) {
            int col = colbase + nt * 16 + l16;
            float bi = bias[col];
#pragma unroll
            for (int r = 0; r < 4; ++r) {
                int row = wm * 16 + q * 4 + r;
                xts[row * 130 + col] = f2bf(fmaxf(acc[wm][nt][r] + bi, 0.0f));
            }
        }
    }
    __syncthreads();
    if (threadIdx.x < 192) {
        int h = threadIdx.x >> 6;           // wave-uniform
        int row = threadIdx.x & 63;
        const float* Wh = (h == 0) ? Wpi : (h == 1) ? Wn : Wp;
        float s = 0.0f;
        const unsigned short* xr = xts + row * 130;
#pragma unroll
        for (int c2 = 0; c2 < 64; ++c2) {
            unsigned u = *(const unsigned*)(xr + c2 * 2);
            s = fmaf(bf2f(u & 0xffffu), Wh[c2 * 2], s);
            s = fmaf(bf2f(u >> 16), Wh[c2 * 2 + 1], s);
        }
        float bb = (h == 0) ? bpi[0] : (h == 1) ? bn[0] : bp[0];
        float z = s + bb;
        float o;
        if (h == 1) o = (z > 20.0f) ? z : log1pf(expf(z));
        else        o = 1.0f / (1.0f + expf(-z));
        out[h * TOT + R0 + row] = o;
    }
}

extern "C" void kernel_launch(void* const* d_in, const int* in_sizes, int n_in,
                              void* d_out, int out_size, void* d_ws, size_t ws_size,
                              hipStream_t stream) {
    const float* x   = (const float*)d_in[0];
    const int*   ei  = (const int*)d_in[1];
    const int*   src = ei;
    const int*   dst = ei + NE;
    const float* W1 = (const float*)d_in[3];
    const float* b1 = (const float*)d_in[4];
    const float* W2 = (const float*)d_in[5];
    const float* b2 = (const float*)d_in[6];
    const float* W3 = (const float*)d_in[7];
    const float* b3 = (const float*)d_in[8];
    const float* tW1 = (const float*)d_in[9];
    const float* tb1 = (const float*)d_in[10];
    const float* tW2 = (const float*)d_in[11];
    const float* tb2 = (const float*)d_in[12];
    const float* tW3 = (const float*)d_in[13];
    const float* tb3 = (const float*)d_in[14];
    const float* Wpi = (const float*)d_in[15];
    const float* bpi = (const float*)d_in[16];
    const float* Wn  = (const float*)d_in[17];
    const float* bn  = (const float*)d_in[18];
    const float* Wp  = (const float*)d_in[19];
    const float* bp  = (const float*)d_in[20];

    // ---- workspace layout ----
    char* ws = (char*)d_ws;
    float* dinv = (float*)(ws + (0ull << 20));            // 512 KB
    int*   gcur = (int*)  (ws + (1ull << 20));            // 64 KB (line-padded)
    int2*  rse  = (int2*) (ws + (1ull << 20) + (256 << 10)); // 1 MB
    unsigned short* wpG1 = (unsigned short*)(ws + (3ull << 20));
    unsigned short* wpG2 = (unsigned short*)(ws + (3ull << 20) + (128 << 10));
    unsigned short* wpG3 = (unsigned short*)(ws + (3ull << 20) + (256 << 10));
    unsigned short* wpC1 = (unsigned short*)(ws + (3ull << 20) + (384 << 10));
    unsigned short* wpC2 = (unsigned short*)(ws + (3ull << 20) + (512 << 10));
    unsigned short* wpC3 = (unsigned short*)(ws + (3ull << 20) + (640 << 10));
    unsigned* buf = (unsigned*)(ws + (4ull << 20));       // 8 MB (NB*BCAP*4B)
    int* adj = (int*)(ws + (12ull << 20));                // 8 MB (NB*BCAP*4B)
    unsigned short* Xa = (unsigned short*)(ws + (24ull  << 20));  // 64ch  16.8 MB
    unsigned short* Xb = (unsigned short*)(ws + (44ull  << 20));  // 128ch 33.6 MB
    unsigned short* Xc = (unsigned short*)(ws + (80ull  << 20));  // 128ch 33.6 MB
    unsigned short* Xd = (unsigned short*)(ws + (116ull << 20));  // 32ch   8.4 MB
    unsigned short* Xe = (unsigned short*)(ws + (128ull << 20));  // 32ch   8.4 MB

    // ---- prep ----
    hipMemsetAsync(gcur, 0, NB * 32 * sizeof(int), stream);
    k_packall<<<352, 256, 0, stream>>>(W1, W2, W3, tW1, tW2, tW3,
                                       wpG1, wpG2, wpG3, wpC1, wpC2, wpC3);

    // ---- adjacency: bucket partition + per-bucket CSR (+ dinv) ----
    k_part<<<NE / EPB, 256, 0, stream>>>(src, dst, gcur, buf);
    k_bcsr<<<NB, 256, 0, stream>>>(buf, gcur, adj, rse, dinv);

    // ---- GCN layer 1: xs = x*dinv; agg; h1 = relu(agg1s@W1+b1) ----
    k_scale64b<<<TOT * 8 / 256, 256, 0, stream>>>((const float4*)x, dinv, (uint4*)Xa);
    k_gcsr<3, 2><<<TOT * 8 / 256, 256, 0, stream>>>((const uint4*)Xa, adj, rse, dinv,
                                                    nullptr, (uint4*)Xb);
    k_mm<64, 128, 1, true, true, false>
        <<<TOT / 64, 256, 0, stream>>>(Xb, (const bf16x8*)wpG1, b1, dinv, Xc);

    // ---- GCN layer 2: zs2 = (h1@W2)*dinv; zs3 = relu(agg*dinv + b2)*dinv ----
    k_mm<128, 32, 1, false, false, true>
        <<<TOT / 64, 256, 0, stream>>>(Xc, (const bf16x8*)wpG2, nullptr, dinv, Xd);
    k_gcsr<2, 1><<<TOT * 4 / 256, 256, 0, stream>>>((const uint4*)Xd, adj, rse, dinv,
                                                    b2, (uint4*)Xe);

    // ---- GCN layer 3: agg3s = agg(zs3)*dinv; h3 = relu(agg3s@W3+b3) ----
    k_gcsr<2, 2><<<TOT * 4 / 256, 256, 0, stream>>>((const uint4*)Xe, adj, rse, dinv,
                                                    nullptr, (uint4*)Xd);
    k_mm<32, 128, 1, true, true, false>
        <<<TOT / 64, 256, 0, stream>>>(Xd, (const bf16x8*)wpG3, b3, dinv, Xb);

    // ---- temporal convs 1,2 ----
    k_mm<128, 128, 3, true, true, false>
        <<<TOT / 64, 256, 0, stream>>>(Xb, (const bf16x8*)wpC1, tb1, nullptr, Xc);
    k_mm<128, 32, 3, true, true, false>
        <<<TOT / 64, 256, 0, stream>>>(Xc, (const bf16x8*)wpC2, tb2, nullptr, Xd);

    // ---- conv3 + heads fused (xt never materialized) ----
    k_conv_heads<<<TOT / 64, 256, 0, stream>>>(Xd, (const bf16x8*)wpC3, tb3,
                                               Wpi, bpi, Wn, bn, Wp, bp, (float*)d_out);
}

// Round 8
// 286.716 us; speedup vs baseline: 3.2885x; 1.0513x over previous
//
#include <hip/hip_runtime.h>
#include <cmath>

// Problem constants (fixed by the reference)
constexpr int TOT = 131072;   // 32 graphs * 4096 nodes
constexpr int NE  = 1048576;  // edges
constexpr int NMASK = 4095;   // N-1, N=4096

// Bucketed adjacency
constexpr int NB   = 512;     // buckets (dst >> 8)
constexpr int DPB  = 256;     // dsts per bucket
constexpr int BCAP = 4096;    // slots per bucket (mean 2048)
constexpr int EPB  = 2048;    // edges per partition block (512 blocks: occupancy fix)

typedef __attribute__((ext_vector_type(8))) short bf16x8;
typedef __attribute__((ext_vector_type(4))) float f32x4;

// ---- bf16 helpers (RNE) ----
__device__ inline float bf2f(unsigned int u16) {
    union { unsigned int i; float f; } x; x.i = u16 << 16; return x.f;
}
__device__ inline unsigned short f2bf(float f) {
    union { float f; unsigned int i; } x; x.f = f;
    unsigned int r = (x.i + 0x7fffu + ((x.i >> 16) & 1u)) >> 16;
    return (unsigned short)r;
}
__device__ inline void unpack8(uint4 v, float* f) {
    f[0] = bf2f(v.x & 0xffffu); f[1] = bf2f(v.x >> 16);
    f[2] = bf2f(v.y & 0xffffu); f[3] = bf2f(v.y >> 16);
    f[4] = bf2f(v.z & 0xffffu); f[5] = bf2f(v.z >> 16);
    f[6] = bf2f(v.w & 0xffffu); f[7] = bf2f(v.w >> 16);
}
__device__ inline uint4 pack8(const float* f) {
    uint4 v;
    v.x = (unsigned)f2bf(f[0]) | ((unsigned)f2bf(f[1]) << 16);
    v.y = (unsigned)f2bf(f[2]) | ((unsigned)f2bf(f[3]) << 16);
    v.z = (unsigned)f2bf(f[4]) | ((unsigned)f2bf(f[5]) << 16);
    v.w = (unsigned)f2bf(f[6]) | ((unsigned)f2bf(f[7]) << 16);
    return v;
}

// ================= edge partition by dst bucket =================
// 512 blocks x 2048 edges (was 128 x 8192: 4.5% occupancy, LDS-atomic
// latency unhidden). gcur is line-padded (one int per 128B).
__global__ __launch_bounds__(256) void k_part(const int* __restrict__ src,
                                              const int* __restrict__ dst,
                                              int* __restrict__ gcur,
                                              unsigned* __restrict__ buf) {
    __shared__ int hist[NB];
    __shared__ int cbase[NB];
    __shared__ int lcur[NB];
    const int tid = threadIdx.x;
    const int e0 = blockIdx.x * EPB;

    for (int b = tid; b < NB; b += 256) hist[b] = 0;
    __syncthreads();
    for (int i = tid; i < EPB; i += 256)
        atomicAdd(&hist[dst[e0 + i] >> 8], 1);
    __syncthreads();
    for (int b = tid; b < NB; b += 256) {
        int c = hist[b];
        cbase[b] = (c > 0) ? atomicAdd(&gcur[b * 32], c) : 0;
        lcur[b] = 0;
    }
    __syncthreads();
    for (int i = tid; i < EPB; i += 256) {
        int e = e0 + i;
        int d = dst[e];
        int b = d >> 8;
        int p = atomicAdd(&lcur[b], 1);
        buf[b * BCAP + cbase[b] + p] = ((unsigned)src[e] << 8) | (unsigned)(d & 255);
    }
}

// ================= per-bucket CSR build =================
__global__ __launch_bounds__(256) void k_bcsr(const unsigned* __restrict__ buf,
                                              const int* __restrict__ gcur,
                                              int* __restrict__ adj,
                                              int2* __restrict__ rse,
                                              float* __restrict__ dinv) {
    __shared__ int cnt[DPB];
    __shared__ int start[DPB];
    __shared__ int cur[DPB];
    __shared__ int sc[DPB];
    const int b = blockIdx.x;
    const int tid = threadIdx.x;
    cnt[tid] = 0;
    __syncthreads();
    const int n = gcur[b * 32];
    const unsigned* eb = buf + b * BCAP;
    for (int i = tid; i < n; i += 256)
        atomicAdd(&cnt[eb[i] & 255u], 1);
    __syncthreads();
    int v = cnt[tid];
    sc[tid] = v;
    __syncthreads();
    for (int off = 1; off < 256; off <<= 1) {
        int a = sc[tid];
        int p = (tid >= off) ? sc[tid - off] : 0;
        __syncthreads();
        sc[tid] = a + p;
        __syncthreads();
    }
    int st = sc[tid] - v;
    start[tid] = st;
    cur[tid] = 0;
    int d = (b << 8) + tid;
    rse[d] = make_int2(b * BCAP + st, v);
    dinv[d] = rsqrtf((float)v + 1.0f);   // +1 self-loop
    __syncthreads();
    for (int i = tid; i < n; i += 256) {
        unsigned w = eb[i];
        int dl = (int)(w & 255u);
        int p = atomicAdd(&cur[dl], 1);
        adj[b * BCAP + start[dl] + p] = (int)(w >> 8);
    }
}

// ================= weight packing into MFMA B-fragment order =================
__global__ __launch_bounds__(256) void k_packall(
    const float* __restrict__ W1, const float* __restrict__ W2, const float* __restrict__ W3,
    const float* __restrict__ tW1, const float* __restrict__ tW2, const float* __restrict__ tW3,
    unsigned short* __restrict__ g1, unsigned short* __restrict__ g2, unsigned short* __restrict__ g3,
    unsigned short* __restrict__ c1, unsigned short* __restrict__ c2, unsigned short* __restrict__ c3) {
    int gid = blockIdx.x * 256 + threadIdx.x;
    const float* w; unsigned short* wp; int CIN, COUT, taps, idx;
    if      (gid <  8192) { w = W1;  wp = g1; CIN = 64;  COUT = 128; taps = 1; idx = gid; }
    else if (gid < 12288) { w = W2;  wp = g2; CIN = 128; COUT = 32;  taps = 1; idx = gid - 8192; }
    else if (gid < 16384) { w = W3;  wp = g3; CIN = 32;  COUT = 128; taps = 1; idx = gid - 12288; }
    else if (gid < 65536) { w = tW1; wp = c1; CIN = 128; COUT = 128; taps = 3; idx = gid - 16384; }
    else if (gid < 77824) { w = tW2; wp = c2; CIN = 128; COUT = 32;  taps = 3; idx = gid - 65536; }
    else if (gid < 90112) { w = tW3; wp = c3; CIN = 32;  COUT = 128; taps = 3; idx = gid - 77824; }
    else return;
    int j = idx & 7;
    int L = (idx >> 3) & 63;
    int f = idx >> 9;
    int NT = COUT >> 4;
    int kc = f / NT, nt = f - kc * NT;
    int k = kc * 32 + (L >> 4) * 8 + j;
    int n = nt * 16 + (L & 15);
    float v;
    if (taps == 1) v = w[k * COUT + n];
    else { int t = k / CIN, c = k - t * CIN; v = w[(n * CIN + c) * 3 + t]; }
    wp[idx] = f2bf(v);
}

// ================= xs = x * dinv -> bf16 (64 ch) =================
__global__ __launch_bounds__(256) void k_scale64b(const float4* __restrict__ x,
                                                  const float* __restrict__ dinv,
                                                  uint4* __restrict__ out) {
    int t = blockIdx.x * 256 + threadIdx.x;   // t < TOT*8
    int row = t >> 3;
    float d = dinv[row];
    float4 v0 = x[t * 2], v1 = x[t * 2 + 1];
    float f[8] = { v0.x * d, v0.y * d, v0.z * d, v0.w * d,
                   v1.x * d, v1.y * d, v1.z * d, v1.w * d };
    out[t] = pack8(f);
}

// ================= standalone CSR gather (layer-2 epilogue only) =================
// out = relu((self+sum)*dinv + bias) * dinv ; LC = log2(C/8) threads per row.
template<int LC>
__global__ __launch_bounds__(256) void k_gcsr(const uint4* __restrict__ xs,
                                              const int* __restrict__ adj,
                                              const int2* __restrict__ rse,
                                              const float* __restrict__ dinv,
                                              const float* __restrict__ bias,
                                              uint4* __restrict__ out) {
    int t = blockIdx.x * 256 + threadIdx.x;   // t < TOT << LC
    int d = t >> LC;
    int g = t & ((1 << LC) - 1);
    float a[8];
    unpack8(xs[t], a);                        // self-loop term
    int2 se = rse[d];
    int e = se.x, end = se.x + se.y;
    for (; e + 4 <= end; e += 4) {
        int s0 = adj[e], s1 = adj[e + 1], s2 = adj[e + 2], s3 = adj[e + 3];
        uint4 v0 = xs[(s0 << LC) + g];
        uint4 v1 = xs[(s1 << LC) + g];
        uint4 v2 = xs[(s2 << LC) + g];
        uint4 v3 = xs[(s3 << LC) + g];
        float f[8];
        unpack8(v0, f);
#pragma unroll
        for (int j = 0; j < 8; ++j) a[j] += f[j];
        unpack8(v1, f);
#pragma unroll
        for (int j = 0; j < 8; ++j) a[j] += f[j];
        unpack8(v2, f);
#pragma unroll
        for (int j = 0; j < 8; ++j) a[j] += f[j];
        unpack8(v3, f);
#pragma unroll
        for (int j = 0; j < 8; ++j) a[j] += f[j];
    }
    for (; e < end; ++e) {
        float f[8];
        unpack8(xs[(adj[e] << LC) + g], f);
#pragma unroll
        for (int j = 0; j < 8; ++j) a[j] += f[j];
    }
    float dv = dinv[d];
#pragma unroll
    for (int j = 0; j < 8; ++j)
        a[j] = fmaxf(fmaf(a[j], dv, bias[g * 8 + j]), 0.0f) * dv;
    out[t] = pack8(a);
}

// ================= fused gather + GEMM (CIN->128, TAPS=1) =================
// Staging phase IS the GCN aggregation: each thread gathers its 1/4-row slice
// agg = (xs[r] + sum_{adj} xs[s]) * dinv[r], packs to bf16 into the LDS tile.
// The gather output tensor (33.6/8.4 MB) never touches HBM.
template<int CIN, bool RELU>
__global__ __launch_bounds__(256) void k_gmm(const uint4* __restrict__ xs,
                                             const int* __restrict__ adj,
                                             const int2* __restrict__ rse,
                                             const float* __restrict__ dinv,
                                             const bf16x8* __restrict__ wp,
                                             const float* __restrict__ bias,
                                             unsigned short* __restrict__ y) {
    constexpr int COUT = 128;
    constexpr int ROWS = 64;
    constexpr int SC = CIN + 8;
    constexpr int NV = CIN / 8;           // uint4s per row
    constexpr int VPT = NV / 4;           // uint4s per thread (4 threads/row)
    constexpr int NK = CIN / 32;
    constexpr int NT = COUT / 16;
    constexpr int WN = 2, WM = 4;
    __shared__ __attribute__((aligned(16))) unsigned short tile[ROWS * SC];

    const int R0 = blockIdx.x * ROWS;
    const int tid = threadIdx.x;

    // ---- gather/stage phase ----
    {
        int r = R0 + (tid >> 2);
        int g = tid & 3;
        const uint4* base = xs + (long)r * NV + g * VPT;
        float a[VPT * 8];
#pragma unroll
        for (int v = 0; v < VPT; ++v) unpack8(base[v], a + v * 8);   // self-loop
        int2 se = rse[r];
        int e = se.x, end = se.x + se.y;
        for (; e + 2 <= end; e += 2) {
            int s0 = adj[e], s1 = adj[e + 1];
            const uint4* p0 = xs + (long)s0 * NV + g * VPT;
            const uint4* p1 = xs + (long)s1 * NV + g * VPT;
            uint4 v0[VPT], v1[VPT];
#pragma unroll
            for (int v = 0; v < VPT; ++v) { v0[v] = p0[v]; v1[v] = p1[v]; }
            float f[VPT * 8];
#pragma unroll
            for (int v = 0; v < VPT; ++v) unpack8(v0[v], f + v * 8);
#pragma unroll
            for (int j = 0; j < VPT * 8; ++j) a[j] += f[j];
#pragma unroll
            for (int v = 0; v < VPT; ++v) unpack8(v1[v], f + v * 8);
#pragma unroll
            for (int j = 0; j < VPT * 8; ++j) a[j] += f[j];
        }
        for (; e < end; ++e) {
            const uint4* p0 = xs + (long)adj[e] * NV + g * VPT;
            float f[VPT * 8];
#pragma unroll
            for (int v = 0; v < VPT; ++v) unpack8(p0[v], f + v * 8);
#pragma unroll
            for (int j = 0; j < VPT * 8; ++j) a[j] += f[j];
        }
        float dv = dinv[r];
#pragma unroll
        for (int j = 0; j < VPT * 8; ++j) a[j] *= dv;
        uint4* dst4 = (uint4*)(tile + (tid >> 2) * SC + g * VPT * 8);
#pragma unroll
        for (int v = 0; v < VPT; ++v) dst4[v] = pack8(a + v * 8);
    }
    __syncthreads();

    // ---- MFMA phase ----
    const int lane = threadIdx.x & 63;
    const int w = threadIdx.x >> 6;
    const int l16 = lane & 15;
    const int q = lane >> 4;
    const int colbase = w * 32;
    const int nt0 = colbase >> 4;

    f32x4 acc[WM][WN];
#pragma unroll
    for (int wm = 0; wm < WM; ++wm)
#pragma unroll
        for (int nt = 0; nt < WN; ++nt) acc[wm][nt] = (f32x4){0.f, 0.f, 0.f, 0.f};

    const bf16x8* __restrict__ wpl = wp + lane;

#pragma unroll
    for (int kc = 0; kc < NK; ++kc) {
        bf16x8 a[WM];
#pragma unroll
        for (int wm = 0; wm < WM; ++wm)
            a[wm] = *(const bf16x8*)(tile + (wm * 16 + l16) * SC + kc * 32 + q * 8);
        bf16x8 b[WN];
#pragma unroll
        for (int nt = 0; nt < WN; ++nt)
            b[nt] = wpl[(kc * NT + nt0 + nt) * 64];
#pragma unroll
        for (int wm = 0; wm < WM; ++wm)
#pragma unroll
            for (int nt = 0; nt < WN; ++nt)
                acc[wm][nt] = __builtin_amdgcn_mfma_f32_16x16x32_bf16(a[wm], b[nt], acc[wm][nt], 0, 0, 0);
    }

#pragma unroll
    for (int wm = 0; wm < WM; ++wm) {
#pragma unroll
        for (int nt = 0; nt < WN; ++nt) {
            int col = colbase + nt * 16 + l16;
            float bi = bias[col];
#pragma unroll
            for (int r = 0; r < 4; ++r) {
                int row = R0 + wm * 16 + q * 4 + r;
                float v = acc[wm][nt][r] + bi;
                if (RELU) v = fmaxf(v, 0.0f);
                y[(long)row * COUT + col] = f2bf(v);
            }
        }
    }
}

// ================= MFMA dense / conv1d =================
template<int CIN, int COUT, int TAPS, bool RELU, bool BIAS, bool SOUT>
__global__ __launch_bounds__(256) void k_mm(const unsigned short* __restrict__ x,
                                            const bf16x8* __restrict__ wp,
                                            const float* __restrict__ bias,
                                            const float* __restrict__ dinv,
                                            unsigned short* __restrict__ y) {
    constexpr int ROWS = 64;
    constexpr int HALO = (TAPS == 3) ? 1 : 0;
    constexpr int TR = ROWS + 2 * HALO;
    constexpr int SC = CIN + 8;
    constexpr int NCH = CIN / 32;
    constexpr int NK = TAPS * NCH;
    constexpr int NT = COUT / 16;
    constexpr int WN = (COUT == 128) ? 2 : 1;
    constexpr int WM = (COUT == 128) ? 4 : 2;
    __shared__ __attribute__((aligned(16))) unsigned short tile[TR * SC];

    const int R0 = blockIdx.x * ROWS;
    const int n0 = R0 & NMASK; (void)n0;

    constexpr int NLD = TR * (CIN / 8);
    for (int idx = threadIdx.x; idx < NLD; idx += 256) {
        int tr = idx / (CIN / 8);
        int c8 = idx - tr * (CIN / 8);
        int ro = tr - HALO;
        bool valid = true;
        if (TAPS == 3) {
            if (ro < 0) valid = (n0 > 0);
            else if (ro >= ROWS) valid = (n0 + ROWS < 4096);
        }
        uint4 v = make_uint4(0, 0, 0, 0);
        if (valid) v = *(const uint4*)(x + (long)(R0 + ro) * CIN + c8 * 8);
        *(uint4*)(tile + tr * SC + c8 * 8) = v;
    }
    __syncthreads();

    const int lane = threadIdx.x & 63;
    const int w = threadIdx.x >> 6;
    const int l16 = lane & 15;
    const int q = lane >> 4;
    const int colbase = (COUT == 128) ? w * 32 : (w & 1) * 16;
    const int rowbase = (COUT == 128) ? 0 : (w >> 1) * 32;
    const int nt0 = colbase >> 4;

    f32x4 acc[WM][WN];
#pragma unroll
    for (int wm = 0; wm < WM; ++wm)
#pragma unroll
        for (int nt = 0; nt < WN; ++nt) acc[wm][nt] = (f32x4){0.f, 0.f, 0.f, 0.f};

    const bf16x8* __restrict__ wpl = wp + lane;

#pragma unroll
    for (int kc = 0; kc < NK; ++kc) {
        const int tap = (TAPS == 3) ? (kc / NCH) : 0;
        const int ch  = (TAPS == 3) ? (kc - tap * NCH) : kc;
        bf16x8 a[WM];
#pragma unroll
        for (int wm = 0; wm < WM; ++wm)
            a[wm] = *(const bf16x8*)(tile + (rowbase + wm * 16 + l16 + tap) * SC + ch * 32 + q * 8);
        bf16x8 b[WN];
#pragma unroll
        for (int nt = 0; nt < WN; ++nt)
            b[nt] = wpl[(kc * NT + nt0 + nt) * 64];
#pragma unroll
        for (int wm = 0; wm < WM; ++wm)
#pragma unroll
            for (int nt = 0; nt < WN; ++nt)
                acc[wm][nt] = __builtin_amdgcn_mfma_f32_16x16x32_bf16(a[wm], b[nt], acc[wm][nt], 0, 0, 0);
    }

    // epilogue: C/D layout col=lane&15, row=q*4+reg
#pragma unroll
    for (int wm = 0; wm < WM; ++wm) {
#pragma unroll
        for (int nt = 0; nt < WN; ++nt) {
            int col = colbase + nt * 16 + l16;
            float bi = BIAS ? bias[col] : 0.0f;
#pragma unroll
            for (int r = 0; r < 4; ++r) {
                int row = R0 + rowbase + wm * 16 + q * 4 + r;
                float v = acc[wm][nt][r] + bi;
                if (RELU) v = fmaxf(v, 0.0f);
                if (SOUT) v *= dinv[row];
                y[(long)row * COUT + col] = f2bf(v);
            }
        }
    }
}

// ================= fused conv3 (32->128, k=3) + heads =================
__global__ __launch_bounds__(256) void k_conv_heads(
    const unsigned short* __restrict__ x, const bf16x8* __restrict__ wp,
    const float* __restrict__ bias,
    const float* __restrict__ Wpi, const float* __restrict__ bpi,
    const float* __restrict__ Wn,  const float* __restrict__ bn,
    const float* __restrict__ Wp,  const float* __restrict__ bp,
    float* __restrict__ out) {
    constexpr int CIN = 32;
    constexpr int ROWS = 64, HALO = 1, TR = 66, SC = CIN + 8;
    constexpr int NK = 3, NT = 8, WN = 2, WM = 4;
    __shared__ __attribute__((aligned(16))) unsigned short tile[TR * SC];
    __shared__ unsigned short xts[64 * 130];

    const int R0 = blockIdx.x * ROWS;
    const int n0 = R0 & NMASK;

    constexpr int NLD = TR * (CIN / 8);
    for (int idx = threadIdx.x; idx < NLD; idx += 256) {
        int tr = idx / (CIN / 8);
        int c8 = idx - tr * (CIN / 8);
        int ro = tr - HALO;
        bool valid = true;
        if (ro < 0) valid = (n0 > 0);
        else if (ro >= ROWS) valid = (n0 + ROWS < 4096);
        uint4 v = make_uint4(0, 0, 0, 0);
        if (valid) v = *(const uint4*)(x + (long)(R0 + ro) * CIN + c8 * 8);
        *(uint4*)(tile + tr * SC + c8 * 8) = v;
    }
    __syncthreads();

    const int lane = threadIdx.x & 63;
    const int w = threadIdx.x >> 6;
    const int l16 = lane & 15;
    const int q = lane >> 4;
    const int colbase = w * 32;
    const int nt0 = colbase >> 4;

    f32x4 acc[WM][WN];
#pragma unroll
    for (int wm = 0; wm < WM; ++wm)
#pragma unroll
        for (int nt = 0; nt < WN; ++nt) acc[wm][nt] = (f32x4){0.f, 0.f, 0.f, 0.f};

    const bf16x8* __restrict__ wpl = wp + lane;

#pragma unroll
    for (int kc = 0; kc < NK; ++kc) {
        bf16x8 a[WM];
#pragma unroll
        for (int wm = 0; wm < WM; ++wm)
            a[wm] = *(const bf16x8*)(tile + (wm * 16 + l16 + kc) * SC + q * 8);
        bf16x8 b[WN];
#pragma unroll
        for (int nt = 0; nt < WN; ++nt)
            b[nt] = wpl[(kc * NT + nt0 + nt) * 64];
#pragma unroll
        for (int wm = 0; wm < WM; ++wm)
#pragma unroll
            for (int nt = 0; nt < WN; ++nt)
                acc[wm][nt] = __builtin_amdgcn_mfma_f32_16x16x32_bf16(a[wm], b[nt], acc[wm][nt], 0, 0, 0);
    }

    // stage xt slab (bf16 round-trip matches the old materialized path)
#pragma unroll
    for (int wm = 0; wm < WM; ++wm) {
#pragma unroll
        for (int nt = 0; nt < WN; ++nt) {
            int col = colbase + nt * 16 + l16;
            float bi = bias[col];
#pragma unroll
            for (int r = 0; r < 4; ++r) {
                int row = wm * 16 + q * 4 + r;
                xts[row * 130 + col] = f2bf(fmaxf(acc[wm][nt][r] + bi, 0.0f));
            }
        }
    }
    __syncthreads();
    if (threadIdx.x < 192) {
        int h = threadIdx.x >> 6;           // wave-uniform
        int row = threadIdx.x & 63;
        const float* Wh = (h == 0) ? Wpi : (h == 1) ? Wn : Wp;
        float s = 0.0f;
        const unsigned short* xr = xts + row * 130;
#pragma unroll
        for (int c2 = 0; c2 < 64; ++c2) {
            unsigned u = *(const unsigned*)(xr + c2 * 2);
            s = fmaf(bf2f(u & 0xffffu), Wh[c2 * 2], s);
            s = fmaf(bf2f(u >> 16), Wh[c2 * 2 + 1], s);
        }
        float bb = (h == 0) ? bpi[0] : (h == 1) ? bn[0] : bp[0];
        float z = s + bb;
        float o;
        if (h == 1) o = (z > 20.0f) ? z : log1pf(expf(z));
        else        o = 1.0f / (1.0f + expf(-z));
        out[h * TOT + R0 + row] = o;
    }
}

extern "C" void kernel_launch(void* const* d_in, const int* in_sizes, int n_in,
                              void* d_out, int out_size, void* d_ws, size_t ws_size,
                              hipStream_t stream) {
    const float* x   = (const float*)d_in[0];
    const int*   ei  = (const int*)d_in[1];
    const int*   src = ei;
    const int*   dst = ei + NE;
    const float* W1 = (const float*)d_in[3];
    const float* b1 = (const float*)d_in[4];
    const float* W2 = (const float*)d_in[5];
    const float* b2 = (const float*)d_in[6];
    const float* W3 = (const float*)d_in[7];
    const float* b3 = (const float*)d_in[8];
    const float* tW1 = (const float*)d_in[9];
    const float* tb1 = (const float*)d_in[10];
    const float* tW2 = (const float*)d_in[11];
    const float* tb2 = (const float*)d_in[12];
    const float* tW3 = (const float*)d_in[13];
    const float* tb3 = (const float*)d_in[14];
    const float* Wpi = (const float*)d_in[15];
    const float* bpi = (const float*)d_in[16];
    const float* Wn  = (const float*)d_in[17];
    const float* bn  = (const float*)d_in[18];
    const float* Wp  = (const float*)d_in[19];
    const float* bp  = (const float*)d_in[20];

    // ---- workspace layout ----
    char* ws = (char*)d_ws;
    float* dinv = (float*)(ws + (0ull << 20));            // 512 KB
    int*   gcur = (int*)  (ws + (1ull << 20));            // 64 KB (line-padded)
    int2*  rse  = (int2*) (ws + (1ull << 20) + (256 << 10)); // 1 MB
    unsigned short* wpG1 = (unsigned short*)(ws + (3ull << 20));
    unsigned short* wpG2 = (unsigned short*)(ws + (3ull << 20) + (128 << 10));
    unsigned short* wpG3 = (unsigned short*)(ws + (3ull << 20) + (256 << 10));
    unsigned short* wpC1 = (unsigned short*)(ws + (3ull << 20) + (384 << 10));
    unsigned short* wpC2 = (unsigned short*)(ws + (3ull << 20) + (512 << 10));
    unsigned short* wpC3 = (unsigned short*)(ws + (3ull << 20) + (640 << 10));
    unsigned* buf = (unsigned*)(ws + (4ull << 20));       // 8 MB (NB*BCAP*4B)
    int* adj = (int*)(ws + (12ull << 20));                // 8 MB (NB*BCAP*4B)
    unsigned short* Xa = (unsigned short*)(ws + (24ull  << 20));  // 64ch  16.8 MB
    unsigned short* Xb = (unsigned short*)(ws + (44ull  << 20));  // 128ch 33.6 MB
    unsigned short* Xc = (unsigned short*)(ws + (80ull  << 20));  // 128ch 33.6 MB
    unsigned short* Xd = (unsigned short*)(ws + (116ull << 20));  // 32ch   8.4 MB
    unsigned short* Xe = (unsigned short*)(ws + (128ull << 20));  // 32ch   8.4 MB

    // ---- prep ----
    hipMemsetAsync(gcur, 0, NB * 32 * sizeof(int), stream);
    k_packall<<<352, 256, 0, stream>>>(W1, W2, W3, tW1, tW2, tW3,
                                       wpG1, wpG2, wpG3, wpC1, wpC2, wpC3);

    // ---- adjacency: bucket partition (512 blocks) + per-bucket CSR (+ dinv) ----
    k_part<<<NE / EPB, 256, 0, stream>>>(src, dst, gcur, buf);
    k_bcsr<<<NB, 256, 0, stream>>>(buf, gcur, adj, rse, dinv);

    // ---- GCN layer 1: xs = x*dinv; fused gather+GEMM -> h1 (Xb never exists) ----
    k_scale64b<<<TOT * 8 / 256, 256, 0, stream>>>((const float4*)x, dinv, (uint4*)Xa);
    k_gmm<64, true><<<TOT / 64, 256, 0, stream>>>((const uint4*)Xa, adj, rse, dinv,
                                                  (const bf16x8*)wpG1, b1, Xc);

    // ---- GCN layer 2: zs2 = (h1@W2)*dinv; zs3 = relu(agg*dinv + b2)*dinv ----
    k_mm<128, 32, 1, false, false, true>
        <<<TOT / 64, 256, 0, stream>>>(Xc, (const bf16x8*)wpG2, nullptr, dinv, Xd);
    k_gcsr<2><<<TOT * 4 / 256, 256, 0, stream>>>((const uint4*)Xd, adj, rse, dinv,
                                                 b2, (uint4*)Xe);

    // ---- GCN layer 3: fused gather+GEMM -> h3 ----
    k_gmm<32, true><<<TOT / 64, 256, 0, stream>>>((const uint4*)Xe, adj, rse, dinv,
                                                  (const bf16x8*)wpG3, b3, Xb);

    // ---- temporal convs 1,2 ----
    k_mm<128, 128, 3, true, true, false>
        <<<TOT / 64, 256, 0, stream>>>(Xb, (const bf16x8*)wpC1, tb1, nullptr, Xc);
    k_mm<128, 32, 3, true, true, false>
        <<<TOT / 64, 256, 0, stream>>>(Xc, (const bf16x8*)wpC2, tb2, nullptr, Xd);

    // ---- conv3 + heads fused (xt never materialized) ----
    k_conv_heads<<<TOT / 64, 256, 0, stream>>>(Xd, (const bf16x8*)wpC3, tb3,
                                               Wpi, bpi, Wn, bn, Wp, bp, (float*)d_out);
}